// Round 2
// baseline (1354.851 us; speedup 1.0000x reference)
//
#include <hip/hip_runtime.h>
#include <hip/hip_bf16.h>

#define BSZ   512
#define SEQ   63
#define DIM   256
#define VDIM  512
#define RREG  196
#define NOUTP 3000
#define SLOTS 8

using f32x4_t  = __attribute__((ext_vector_type(4))) float;
using bf16x8_t = __attribute__((ext_vector_type(8))) short;

__device__ inline float bf2f(unsigned short u){
  union { unsigned int i; float f; } x; x.i = ((unsigned int)u) << 16; return x.f;
}
__device__ inline unsigned short f2bf(float f){
  unsigned int u = __float_as_uint(f);
  unsigned int r = (u + 0x7fffu + ((u >> 16) & 1u)) >> 16;   // RNE
  return (unsigned short)r;
}
__device__ inline unsigned int bfpack(float a, float b){
  return (unsigned int)f2bf(a) | ((unsigned int)f2bf(b) << 16);
}
__device__ inline void bf2x(unsigned int w, float& a, float& b){
  union { unsigned int i; float f; } x, y;
  x.i = w << 16; y.i = w & 0xffff0000u; a = x.f; b = y.f;
}
__device__ inline float sigm(float x){ return 1.f / (1.f + __expf(-x)); }
__device__ inline float ftanh(float x){ return 1.f - 2.f / (__expf(2.f * x) + 1.f); }

__device__ inline f32x4_t mfma16(bf16x8_t a, bf16x8_t b, f32x4_t c){
  return __builtin_amdgcn_mfma_f32_16x16x32_bf16(a, b, c, 0, 0, 0);
}

// ---------------- workspace layout (bytes) -- total 55,574,528 ----------------
#define OFF_WWBF   0u
#define OFF_WIBF   262144u
#define OFF_WUBF   393216u
#define OFF_WOBF   524288u
#define OFF_UIBF   655360u
#define OFF_UFBF   786432u
#define OFF_UOBF   917504u
#define OFF_UUBF   1048576u
#define OFF_WVBF   1179648u
#define OFF_WQBF   1310720u
#define OFF_FC1BF  1441792u
#define OFF_FC2BF  1572864u            // (768000+2048)*2 = 1,540,096 -> ends 3,112,960
#define OFF_RVEC   3112960u            // 512*256*4 = 524,288
#define OFF_Z      3637248u            // 512*256*4
#define OFF_STACKH 4194304u            // 512*8*256*4 = 4,194,304
#define OFF_STACKC 8388608u
#define OFF_BH     12582912u           // 512*63*256*2 = 16,515,072
#define OFF_BC     29097984u
#define OFF_VVB    4194304u            // OVERLAY on stacks+bh/bc; written after tree kernel
                                       // 512*196*256*2 = 51,380,224 -> ends 55,574,528

// ---------------- K0: fp32 -> bf16 weight conversion ----------------
struct ConvArgs {
  const float* src[13];
  unsigned short* dst[13];
  int n[13];
};

__global__ __launch_bounds__(256) void k0_convert(ConvArgs a){
  const int gid = blockIdx.x * 256 + threadIdx.x;
  const int stride = gridDim.x * 256;
  #pragma unroll 1
  for (int j = 0; j < 13; ++j){
    const float* s = a.src[j];
    unsigned short* d = a.dst[j];
    const int n = a.n[j];
    if (s){
      for (int i = gid; i < n; i += stride) d[i] = f2bf(s[i]);
    } else {
      for (int i = gid; i < n; i += stride) d[i] = 0;
    }
  }
}

// ---------------- K1: leaf gates (bh, bc) ----------------
__global__ __launch_bounds__(256) void k1_leaf(
    const int* __restrict__ questions, const float* __restrict__ wembed,
    const unsigned short* __restrict__ Wi, const unsigned short* __restrict__ Wu,
    const unsigned short* __restrict__ Wo,
    const float* __restrict__ Wib, const float* __restrict__ Wub, const float* __restrict__ Wob,
    unsigned short* __restrict__ bh, unsigned short* __restrict__ bc)
{
  __shared__ unsigned short qt[64][264];
  __shared__ int qidx[64];
  const int tid = threadIdx.x;
  const int row0 = blockIdx.x * 64;
  if (tid < 64) qidx[tid] = questions[row0 + tid];
  __syncthreads();
  {
    const int mb = tid >> 4, c = (tid & 15) * 16;
    #pragma unroll
    for (int rr = 0; rr < 4; ++rr){
      const int m = mb + rr * 16;
      const float* src = wembed + (size_t)qidx[m] * DIM + c;
      #pragma unroll
      for (int k = 0; k < 16; k += 4){
        float4 x = *(const float4*)(src + k);
        *(unsigned int*)&qt[m][c + k]     = bfpack(x.x, x.y);
        *(unsigned int*)&qt[m][c + k + 2] = bfpack(x.z, x.w);
      }
    }
  }
  __syncthreads();
  const int lane = tid & 63, wv = tid >> 6;
  const int lr = lane & 15, lk = (lane >> 4) * 8;
  for (int et = 0; et < 4; ++et){
    const int e = et * 64 + wv * 16 + lr;
    bf16x8_t Bi[8], Bu[8], Bo[8];
    const size_t wb = (size_t)e * DIM + lk;
    #pragma unroll
    for (int kk = 0; kk < 8; ++kk){
      Bi[kk] = *(const bf16x8_t*)(Wi + wb + kk * 32);
      Bu[kk] = *(const bf16x8_t*)(Wu + wb + kk * 32);
      Bo[kk] = *(const bf16x8_t*)(Wo + wb + kk * 32);
    }
    const float bi = Wib[e], bu = Wub[e], bo = Wob[e];
    for (int mt = 0; mt < 4; ++mt){
      f32x4_t ai = {0,0,0,0}, au = {0,0,0,0}, ao = {0,0,0,0};
      const unsigned short* ar = &qt[mt * 16 + lr][lk];
      #pragma unroll
      for (int kk = 0; kk < 8; ++kk){
        bf16x8_t A = *(const bf16x8_t*)(ar + kk * 32);
        ai = mfma16(A, Bi[kk], ai);
        au = mfma16(A, Bu[kk], au);
        ao = mfma16(A, Bo[kk], ao);
      }
      #pragma unroll
      for (int j = 0; j < 4; ++j){
        const int m = mt * 16 + (lane >> 4) * 4 + j;
        const float ig = sigm(ai[j] + bi), ug = ftanh(au[j] + bu), og = sigm(ao[j] + bo);
        const float cc = ig * ug, hh = og * ftanh(cc);
        const size_t o = (size_t)(row0 + m) * DIM + e;
        bc[o] = f2bf(cc); bh[o] = f2bf(hh);
      }
    }
  }
}

// ---------------- K2: tree scan, 32 blocks x 16 rows ----------------
__global__ __launch_bounds__(256) void k2_tree(
    const int* __restrict__ ops,
    const unsigned short* __restrict__ bh, const unsigned short* __restrict__ bc,
    const unsigned short* __restrict__ Ui, const unsigned short* __restrict__ Uf,
    const unsigned short* __restrict__ Uo, const unsigned short* __restrict__ Uu,
    const float* __restrict__ Uib, const float* __restrict__ Ufb,
    const float* __restrict__ Uob, const float* __restrict__ Uub,
    float* __restrict__ stack_h, float* __restrict__ stack_c, float* __restrict__ r_vec)
{
  __shared__ unsigned short HS[16][264];
  __shared__ unsigned short H1[16][264];
  __shared__ unsigned short H2[16][264];
  __shared__ float C1[16 * 256];
  __shared__ float C2[16 * 256];
  __shared__ int opm[16], ptrv[16], lidx[16], ridx[16];
  const int tid = threadIdx.x;
  const int lane = tid & 63, wv = tid >> 6;
  const int lr = lane & 15, lk = (lane >> 4) * 8;
  const int rb = blockIdx.x * 16;
  if (tid < 16) ptrv[tid] = 0;

  for (int s = 0; s < SEQ; ++s){
    __syncthreads();
    if (tid < 16){
      opm[tid] = ops[(size_t)(rb + tid) * SEQ + s];
      const int p = ptrv[tid];
      lidx[tid] = (p - 2 > 0) ? (p - 2) : 0;
      ridx[tid] = (p - 1 > 0) ? (p - 1) : 0;
    }
    __syncthreads();
    bool anyred = false, anypush = false;
    #pragma unroll
    for (int m = 0; m < 16; ++m){ const int o = opm[m]; anyred |= (o == 1); anypush |= (o == 0); }

    if (anyred){
      {
        const int m = tid >> 4, c = (tid & 15) * 16;
        const float* shp = stack_h + (size_t)(rb + m) * SLOTS * DIM;
        const float* scp = stack_c + (size_t)(rb + m) * SLOTS * DIM;
        const int li = lidx[m] * DIM + c, ri = ridx[m] * DIM + c;
        #pragma unroll
        for (int k = 0; k < 16; k += 4){
          float4 h1 = *(const float4*)(shp + li + k);
          float4 h2 = *(const float4*)(shp + ri + k);
          float4 c1 = *(const float4*)(scp + li + k);
          float4 c2 = *(const float4*)(scp + ri + k);
          *(unsigned int*)&H1[m][c + k]     = bfpack(h1.x, h1.y);
          *(unsigned int*)&H1[m][c + k + 2] = bfpack(h1.z, h1.w);
          *(unsigned int*)&H2[m][c + k]     = bfpack(h2.x, h2.y);
          *(unsigned int*)&H2[m][c + k + 2] = bfpack(h2.z, h2.w);
          *(unsigned int*)&HS[m][c + k]     = bfpack(h1.x + h2.x, h1.y + h2.y);
          *(unsigned int*)&HS[m][c + k + 2] = bfpack(h1.z + h2.z, h1.w + h2.w);
          *(float4*)(C1 + m * DIM + c + k) = c1;
          *(float4*)(C2 + m * DIM + c + k) = c2;
        }
      }
      __syncthreads();
      for (int et = 0; et < 4; ++et){
        const int e = wv * 64 + et * 16 + lr;
        f32x4_t ai = {0,0,0,0}, ao = {0,0,0,0}, au = {0,0,0,0}, a1 = {0,0,0,0}, a2 = {0,0,0,0};
        const size_t wb = (size_t)e * DIM + lk;
        const unsigned short *pS = &HS[lr][lk], *p1 = &H1[lr][lk], *p2 = &H2[lr][lk];
        #pragma unroll
        for (int kk = 0; kk < 8; ++kk){
          bf16x8_t AS = *(const bf16x8_t*)(pS + kk * 32);
          bf16x8_t A1 = *(const bf16x8_t*)(p1 + kk * 32);
          bf16x8_t A2 = *(const bf16x8_t*)(p2 + kk * 32);
          bf16x8_t Wi_ = *(const bf16x8_t*)(Ui + wb + kk * 32);
          bf16x8_t Wo_ = *(const bf16x8_t*)(Uo + wb + kk * 32);
          bf16x8_t Wu_ = *(const bf16x8_t*)(Uu + wb + kk * 32);
          bf16x8_t Wf_ = *(const bf16x8_t*)(Uf + wb + kk * 32);
          ai = mfma16(AS, Wi_, ai);
          ao = mfma16(AS, Wo_, ao);
          au = mfma16(AS, Wu_, au);
          a1 = mfma16(A1, Wf_, a1);
          a2 = mfma16(A2, Wf_, a2);
        }
        const float bi = Uib[e], bo = Uob[e], bu = Uub[e], bfb = Ufb[e];
        #pragma unroll
        for (int j = 0; j < 4; ++j){
          const int m = (lane >> 4) * 4 + j;
          if (opm[m] == 1){
            const float ig = sigm(ai[j] + bi), og = sigm(ao[j] + bo), ug = ftanh(au[j] + bu);
            const float f1 = sigm(a1[j] + bfb), f2 = sigm(a2[j] + bfb);
            const float cn = ig * ug + f1 * C1[m * DIM + e] + f2 * C2[m * DIM + e];
            const float hn = og * ftanh(cn);
            const size_t o = ((size_t)(rb + m) * SLOTS + lidx[m]) * DIM + e;
            stack_h[o] = hn; stack_c[o] = cn;
          }
        }
      }
    }
    if (anypush){
      const int m = tid >> 4, c = (tid & 15) * 16;
      if (opm[m] == 0){
        const int wslot = (ptrv[m] < SLOTS - 1) ? ptrv[m] : (SLOTS - 1);
        const size_t so = ((size_t)(rb + m) * SEQ + s) * DIM + c;
        const size_t dofs = ((size_t)(rb + m) * SLOTS + wslot) * DIM + c;
        #pragma unroll
        for (int k = 0; k < 16; ++k){
          stack_h[dofs + k] = bf2f(bh[so + k]);
          stack_c[dofs + k] = bf2f(bc[so + k]);
        }
      }
    }
    __syncthreads();
    if (tid < 16){
      const int o = opm[tid];
      ptrv[tid] += (o == 0) ? 1 : ((o == 1) ? -1 : 0);
    }
  }
  __syncthreads();
  {
    const int m = tid >> 4, c = (tid & 15) * 16;
    int p = ptrv[m] - 1;
    p = (p > 0) ? p : 0;
    p = (p < SLOTS - 1) ? p : (SLOTS - 1);
    const size_t so = ((size_t)(rb + m) * SLOTS + p) * DIM + c;
    float* dst = r_vec + (size_t)(rb + m) * DIM + c;
    #pragma unroll
    for (int k = 0; k < 16; k += 4) *(float4*)(dst + k) = *(const float4*)(stack_h + so + k);
  }
}

// ---------------- K3: vv = tanh(v @ W_w^T + W_b), 32 rows/block ----------------
__global__ __launch_bounds__(256) void k3_vv(
    const float* __restrict__ v, const unsigned short* __restrict__ Wwbf,
    const float* __restrict__ W_b, unsigned short* __restrict__ vv)
{
  __shared__ unsigned short vt[32][520];
  const int tid = threadIdx.x;
  const int lane = tid & 63, wv = tid >> 6;
  const int lr = lane & 15, lk = (lane >> 4) * 8;
  const size_t row0 = (size_t)blockIdx.x * 32;
  {
    const int mb = tid >> 4, c = (tid & 15) * 32;
    #pragma unroll
    for (int rr = 0; rr < 2; ++rr){
      const int m = mb + rr * 16;
      const float* src = v + (row0 + m) * VDIM + c;
      #pragma unroll
      for (int k = 0; k < 32; k += 4){
        float4 x = *(const float4*)(src + k);
        *(unsigned int*)&vt[m][c + k]     = bfpack(x.x, x.y);
        *(unsigned int*)&vt[m][c + k + 2] = bfpack(x.z, x.w);
      }
    }
  }
  __syncthreads();
  for (int et = 0; et < 4; ++et){
    const int e = et * 64 + wv * 16 + lr;
    bf16x8_t Bv[16];
    const size_t wb = (size_t)e * VDIM + lk;
    #pragma unroll
    for (int kk = 0; kk < 16; ++kk) Bv[kk] = *(const bf16x8_t*)(Wwbf + wb + kk * 32);
    const float bias = W_b[e];
    for (int mt = 0; mt < 2; ++mt){
      f32x4_t acc = {0,0,0,0};
      const unsigned short* ar = &vt[mt * 16 + lr][lk];
      #pragma unroll
      for (int kk = 0; kk < 16; ++kk){
        bf16x8_t A = *(const bf16x8_t*)(ar + kk * 32);
        acc = mfma16(A, Bv[kk], acc);
      }
      #pragma unroll
      for (int j = 0; j < 4; ++j){
        const int m = mt * 16 + (lane >> 4) * 4 + j;
        vv[(row0 + m) * DIM + e] = f2bf(ftanh(acc[j] + bias));
      }
    }
  }
}

// ---------------- K4: per-batch attention + FC1 ----------------
__global__ __launch_bounds__(256) void k4_attn(
    const unsigned short* __restrict__ vv, const float* __restrict__ r_vec,
    const unsigned short* __restrict__ WQbf, const float* __restrict__ WQb,
    const unsigned short* __restrict__ WVbf, const float* __restrict__ WPw,
    const unsigned short* __restrict__ FC1bf, const float* __restrict__ FC1b,
    float* __restrict__ z)
{
  __shared__ float rld[256];
  __shared__ float wqv[256];
  __shared__ unsigned short vt[16][264];
  __shared__ float pre[16 * 256];
  __shared__ float scv[208];
  __shared__ float red[8];
  __shared__ float attv[256];
  const int b = blockIdx.x, tid = threadIdx.x;
  const int lane = tid & 63, wv = tid >> 6;
  const int lr = lane & 15, lk = (lane >> 4) * 8;

  rld[tid] = r_vec[(size_t)b * DIM + tid];
  __syncthreads();
  {
    float acc = WQb[tid];
    const unsigned short* wr = WQbf + (size_t)tid * DIM;
    for (int d = 0; d < DIM; d += 8){
      uint4 w4 = *(const uint4*)(wr + d);
      float a0,a1,a2,a3,a4,a5,a6,a7;
      bf2x(w4.x,a0,a1); bf2x(w4.y,a2,a3); bf2x(w4.z,a4,a5); bf2x(w4.w,a6,a7);
      acc += a0*rld[d] + a1*rld[d+1] + a2*rld[d+2] + a3*rld[d+3]
           + a4*rld[d+4] + a5*rld[d+5] + a6*rld[d+6] + a7*rld[d+7];
    }
    wqv[tid] = acc;
  }
  for (int rt = 0; rt < 13; ++rt){
    __syncthreads();
    {
      const int m = tid >> 4, c = (tid & 15) * 16;
      const int rr = rt * 16 + m;
      if (rr < RREG){
        const unsigned short* src = vv + ((size_t)b * RREG + rr) * DIM + c;
        *(uint4*)&vt[m][c]     = *(const uint4*)(src);
        *(uint4*)&vt[m][c + 8] = *(const uint4*)(src + 8);
      } else {
        uint4 zz = {0,0,0,0};
        *(uint4*)&vt[m][c] = zz; *(uint4*)&vt[m][c + 8] = zz;
      }
    }
    __syncthreads();
    for (int et = 0; et < 4; ++et){
      const int e = wv * 64 + et * 16 + lr;
      f32x4_t acc = {0,0,0,0};
      const size_t wb = (size_t)e * DIM + lk;
      const unsigned short* ar = &vt[lr][lk];
      #pragma unroll
      for (int kk = 0; kk < 8; ++kk){
        bf16x8_t A = *(const bf16x8_t*)(ar + kk * 32);
        bf16x8_t Bb = *(const bf16x8_t*)(WVbf + wb + kk * 32);
        acc = mfma16(A, Bb, acc);
      }
      const float wqe = wqv[e];
      #pragma unroll
      for (int j = 0; j < 4; ++j){
        const int m = (lane >> 4) * 4 + j;
        pre[m * DIM + e] = ftanh(acc[j] + wqe);
      }
    }
    __syncthreads();
    {
      const int m = tid >> 4, cc = (tid & 15) * 16;
      float p_ = 0.f;
      #pragma unroll
      for (int k = 0; k < 16; ++k) p_ += pre[m * DIM + cc + k] * WPw[cc + k];
      #pragma unroll
      for (int off = 8; off; off >>= 1) p_ += __shfl_xor(p_, off, 16);
      if ((tid & 15) == 0){
        const int rr = rt * 16 + m;
        scv[rr] = (rr < RREG) ? p_ : -1e30f;
      }
    }
  }
  __syncthreads();
  {
    const float sv = (tid < RREG) ? scv[tid] : -1e30f;
    float m_ = sv;
    #pragma unroll
    for (int off = 32; off; off >>= 1) m_ = fmaxf(m_, __shfl_xor(m_, off, 64));
    if (lane == 0) red[wv] = m_;
    __syncthreads();
    m_ = fmaxf(fmaxf(red[0], red[1]), fmaxf(red[2], red[3]));
    const float ex = (tid < RREG) ? __expf(sv - m_) : 0.f;
    float s_ = ex;
    #pragma unroll
    for (int off = 32; off; off >>= 1) s_ += __shfl_xor(s_, off, 64);
    if (lane == 0) red[4 + wv] = s_;
    __syncthreads();
    s_ = red[4] + red[5] + red[6] + red[7];
    if (tid < RREG) scv[tid] = ex / s_;
  }
  __syncthreads();
  {
    float a = rld[tid];
    const unsigned short* base = vv + (size_t)b * RREG * DIM + tid;
    #pragma unroll 4
    for (int rr = 0; rr < RREG; ++rr) a += scv[rr] * bf2f(base[(size_t)rr * DIM]);
    attv[tid] = a;
  }
  __syncthreads();
  {
    float acc = FC1b[tid];
    const unsigned short* wr = FC1bf + (size_t)tid * DIM;
    for (int d = 0; d < DIM; d += 8){
      uint4 w4 = *(const uint4*)(wr + d);
      float a0,a1,a2,a3,a4,a5,a6,a7;
      bf2x(w4.x,a0,a1); bf2x(w4.y,a2,a3); bf2x(w4.z,a4,a5); bf2x(w4.w,a6,a7);
      acc += a0*attv[d] + a1*attv[d+1] + a2*attv[d+2] + a3*attv[d+3]
           + a4*attv[d+4] + a5*attv[d+5] + a6*attv[d+6] + a7*attv[d+7];
    }
    z[(size_t)b * DIM + tid] = ftanh(acc);
  }
}

// ---------------- K5: FC2 ----------------
__global__ __launch_bounds__(256) void k5_fc2(
    const float* __restrict__ z, const unsigned short* __restrict__ FC2bf,
    const float* __restrict__ FC2b, float* __restrict__ out)
{
  __shared__ unsigned short zt[16][264];
  const int tid = threadIdx.x;
  const int rb = blockIdx.x * 16, ob = blockIdx.y * 64;
  {
    const int m = tid >> 4, c = (tid & 15) * 16;
    const float* src = z + (size_t)(rb + m) * DIM + c;
    #pragma unroll
    for (int k = 0; k < 16; k += 4){
      float4 x = *(const float4*)(src + k);
      *(unsigned int*)&zt[m][c + k]     = bfpack(x.x, x.y);
      *(unsigned int*)&zt[m][c + k + 2] = bfpack(x.z, x.w);
    }
  }
  __syncthreads();
  const int lane = tid & 63, wv = tid >> 6;
  const int lr = lane & 15, lk = (lane >> 4) * 8;
  const int o = ob + wv * 16 + lr;
  f32x4_t acc = {0,0,0,0};
  const size_t wb = (size_t)o * DIM + lk;
  const unsigned short* ar = &zt[lr][lk];
  #pragma unroll
  for (int kk = 0; kk < 8; ++kk){
    bf16x8_t A = *(const bf16x8_t*)(ar + kk * 32);
    bf16x8_t Bb = *(const bf16x8_t*)(FC2bf + wb + kk * 32);
    acc = mfma16(A, Bb, acc);
  }
  if (o < NOUTP){
    const float bo = FC2b[o];
    #pragma unroll
    for (int j = 0; j < 4; ++j){
      const int m = (lane >> 4) * 4 + j;
      out[(size_t)(rb + m) * NOUTP + o] = acc[j] + bo;
    }
  }
}

// ---------------- launch ----------------
extern "C" void kernel_launch(void* const* d_in, const int* in_sizes, int n_in,
                              void* d_out, int out_size, void* d_ws, size_t ws_size,
                              hipStream_t stream) {
  const float* v         = (const float*)d_in[0];
  const int*   questions = (const int*)d_in[1];
  const int*   ops       = (const int*)d_in[2];
  const float* wembed    = (const float*)d_in[4];
  const float* W_w  = (const float*)d_in[5];   const float* W_b  = (const float*)d_in[6];
  const float* Wi_w = (const float*)d_in[7];   const float* Wi_b = (const float*)d_in[8];
  const float* Wu_w = (const float*)d_in[9];   const float* Wu_b = (const float*)d_in[10];
  const float* Wo_w = (const float*)d_in[11];  const float* Wo_b = (const float*)d_in[12];
  const float* Ui_w = (const float*)d_in[13];  const float* Ui_b = (const float*)d_in[14];
  const float* Uf_w = (const float*)d_in[15];  const float* Uf_b = (const float*)d_in[16];
  const float* Uo_w = (const float*)d_in[17];  const float* Uo_b = (const float*)d_in[18];
  const float* Uu_w = (const float*)d_in[19];  const float* Uu_b = (const float*)d_in[20];
  const float* WQ_w = (const float*)d_in[21];  const float* WQ_b = (const float*)d_in[22];
  const float* WV_w = (const float*)d_in[23];
  const float* WP_w = (const float*)d_in[24];
  const float* FC1_w = (const float*)d_in[26]; const float* FC1_b = (const float*)d_in[27];
  const float* FC2_w = (const float*)d_in[28]; const float* FC2_b = (const float*)d_in[29];
  float* out = (float*)d_out;
  char* ws = (char*)d_ws;

  unsigned short* Wwbf  = (unsigned short*)(ws + OFF_WWBF);
  unsigned short* Wibf  = (unsigned short*)(ws + OFF_WIBF);
  unsigned short* Wubf  = (unsigned short*)(ws + OFF_WUBF);
  unsigned short* Wobf  = (unsigned short*)(ws + OFF_WOBF);
  unsigned short* Uibf  = (unsigned short*)(ws + OFF_UIBF);
  unsigned short* Ufbf  = (unsigned short*)(ws + OFF_UFBF);
  unsigned short* Uobf  = (unsigned short*)(ws + OFF_UOBF);
  unsigned short* Uubf  = (unsigned short*)(ws + OFF_UUBF);
  unsigned short* WVbf  = (unsigned short*)(ws + OFF_WVBF);
  unsigned short* WQbf  = (unsigned short*)(ws + OFF_WQBF);
  unsigned short* FC1bf = (unsigned short*)(ws + OFF_FC1BF);
  unsigned short* FC2bf = (unsigned short*)(ws + OFF_FC2BF);
  float* r_vec   = (float*)(ws + OFF_RVEC);
  float* z       = (float*)(ws + OFF_Z);
  float* stack_h = (float*)(ws + OFF_STACKH);
  float* stack_c = (float*)(ws + OFF_STACKC);
  unsigned short* bh  = (unsigned short*)(ws + OFF_BH);
  unsigned short* bc  = (unsigned short*)(ws + OFF_BC);
  unsigned short* vvb = (unsigned short*)(ws + OFF_VVB);   // overlay, used after k2

  // zero both stacks (reference semantics: unwritten slots read as 0)
  hipMemsetAsync(ws + OFF_STACKH, 0, 8388608, stream);

  ConvArgs ca;
  const float* srcs[13] = { W_w, Wi_w, Wu_w, Wo_w, Ui_w, Uf_w, Uo_w, Uu_w, WV_w, WQ_w, FC1_w, FC2_w, nullptr };
  unsigned short* dsts[13] = { Wwbf, Wibf, Wubf, Wobf, Uibf, Ufbf, Uobf, Uubf, WVbf, WQbf, FC1bf, FC2bf, FC2bf + 768000 };
  int ns[13] = { 131072, 65536, 65536, 65536, 65536, 65536, 65536, 65536, 65536, 65536, 65536, 768000, 2048 };
  for (int i = 0; i < 13; ++i){ ca.src[i] = srcs[i]; ca.dst[i] = dsts[i]; ca.n[i] = ns[i]; }
  k0_convert<<<512, 256, 0, stream>>>(ca);

  k1_leaf<<<504, 256, 0, stream>>>(questions, wembed, Wibf, Wubf, Wobf, Wi_b, Wu_b, Wo_b, bh, bc);

  k2_tree<<<32, 256, 0, stream>>>(ops, bh, bc, Uibf, Ufbf, Uobf, Uubf,
                                  Ui_b, Uf_b, Uo_b, Uu_b,
                                  stack_h, stack_c, r_vec);

  // vvb overlays stacks+bh/bc -> must run after k2_tree
  k3_vv<<<3136, 256, 0, stream>>>(v, Wwbf, W_b, vvb);

  k4_attn<<<512, 256, 0, stream>>>(vvb, r_vec, WQbf, WQ_b, WVbf, WP_w, FC1bf, FC1_b, z);

  k5_fc2<<<dim3(32, 47), 256, 0, stream>>>(z, FC2bf, FC2_b, out);

  (void)in_sizes; (void)n_in; (void)out_size; (void)ws_size;
}

// Round 5
// 1127.249 us; speedup vs baseline: 1.2019x; 1.2019x over previous
//
#include <hip/hip_runtime.h>
#include <hip/hip_bf16.h>

#define BSZ   512
#define SEQ   63
#define DIM   256
#define VDIM  512
#define RREG  196
#define NOUTP 3000

using f32x4_t  = __attribute__((ext_vector_type(4))) float;
using bf16x8_t = __attribute__((ext_vector_type(8))) short;

__device__ inline float bf2f(unsigned short u){
  union { unsigned int i; float f; } x; x.i = ((unsigned int)u) << 16; return x.f;
}
__device__ inline unsigned short f2bf(float f){
  unsigned int u = __float_as_uint(f);
  unsigned int r = (u + 0x7fffu + ((u >> 16) & 1u)) >> 16;   // RNE
  return (unsigned short)r;
}
__device__ inline unsigned int bfpack(float a, float b){
  return (unsigned int)f2bf(a) | ((unsigned int)f2bf(b) << 16);
}
__device__ inline void bf2x(unsigned int w, float& a, float& b){
  union { unsigned int i; float f; } x, y;
  x.i = w << 16; y.i = w & 0xffff0000u; a = x.f; b = y.f;
}
__device__ inline float sigm(float x){ return 1.f / (1.f + __expf(-x)); }
__device__ inline float ftanh(float x){ return 1.f - 2.f / (__expf(2.f * x) + 1.f); }

__device__ inline f32x4_t mfma16(bf16x8_t a, bf16x8_t b, f32x4_t c){
  return __builtin_amdgcn_mfma_f32_16x16x32_bf16(a, b, c, 0, 0, 0);
}

// ---------------- workspace layout (bytes) -- total 37,191,680 ----------------
#define OFF_WWBF   0u
#define OFF_WIBF   262144u
#define OFF_WUBF   393216u
#define OFF_WOBF   524288u
#define OFF_UIBF   655360u
#define OFF_UFBF   786432u
#define OFF_UOBF   917504u
#define OFF_UUBF   1048576u
#define OFF_WVBF   1179648u
#define OFF_WQBF   1310720u
#define OFF_FC1BF  1441792u
#define OFF_FC2BF  1572864u            // (768000+2048)*2 -> ends 3,112,960
#define OFF_RVEC   3112960u
#define OFF_Z      3637248u
#define OFF_BH     4161536u            // 512*63*256*2 = 16,515,072
#define OFF_BC     20676608u           // -> ends 37,191,680

// ---------------- K0: fp32 -> bf16 weight conversion ----------------
struct ConvArgs {
  const float* src[13];
  unsigned short* dst[13];
  int n[13];
};

__global__ __launch_bounds__(256) void k0_convert(ConvArgs a){
  const int gid = blockIdx.x * 256 + threadIdx.x;
  const int stride = gridDim.x * 256;
  #pragma unroll 1
  for (int j = 0; j < 13; ++j){
    const float* s = a.src[j];
    unsigned short* d = a.dst[j];
    const int n = a.n[j];
    if (s){
      for (int i = gid; i < n; i += stride) d[i] = f2bf(s[i]);
    } else {
      for (int i = gid; i < n; i += stride) d[i] = 0;
    }
  }
}

// ---------------- K1: leaf gates (bh, bc) ----------------
__global__ __launch_bounds__(256) void k1_leaf(
    const int* __restrict__ questions, const float* __restrict__ wembed,
    const unsigned short* __restrict__ Wi, const unsigned short* __restrict__ Wu,
    const unsigned short* __restrict__ Wo,
    const float* __restrict__ Wib, const float* __restrict__ Wub, const float* __restrict__ Wob,
    unsigned short* __restrict__ bh, unsigned short* __restrict__ bc)
{
  __shared__ unsigned short qt[64][264];
  __shared__ int qidx[64];
  const int tid = threadIdx.x;
  const int row0 = blockIdx.x * 64;
  if (tid < 64) qidx[tid] = questions[row0 + tid];
  __syncthreads();
  {
    const int mb = tid >> 4, c = (tid & 15) * 16;
    #pragma unroll
    for (int rr = 0; rr < 4; ++rr){
      const int m = mb + rr * 16;
      const float* src = wembed + (size_t)qidx[m] * DIM + c;
      #pragma unroll
      for (int k = 0; k < 16; k += 4){
        float4 x = *(const float4*)(src + k);
        *(unsigned int*)&qt[m][c + k]     = bfpack(x.x, x.y);
        *(unsigned int*)&qt[m][c + k + 2] = bfpack(x.z, x.w);
      }
    }
  }
  __syncthreads();
  const int lane = tid & 63, wv = tid >> 6;
  const int lr = lane & 15, lk = (lane >> 4) * 8;
  for (int et = 0; et < 4; ++et){
    const int e = et * 64 + wv * 16 + lr;
    bf16x8_t Bi[8], Bu[8], Bo[8];
    const size_t wb = (size_t)e * DIM + lk;
    #pragma unroll
    for (int kk = 0; kk < 8; ++kk){
      Bi[kk] = *(const bf16x8_t*)(Wi + wb + kk * 32);
      Bu[kk] = *(const bf16x8_t*)(Wu + wb + kk * 32);
      Bo[kk] = *(const bf16x8_t*)(Wo + wb + kk * 32);
    }
    const float bi = Wib[e], bu = Wub[e], bo = Wob[e];
    for (int mt = 0; mt < 4; ++mt){
      f32x4_t ai = {0,0,0,0}, au = {0,0,0,0}, ao = {0,0,0,0};
      const unsigned short* ar = &qt[mt * 16 + lr][lk];
      #pragma unroll
      for (int kk = 0; kk < 8; ++kk){
        bf16x8_t A = *(const bf16x8_t*)(ar + kk * 32);
        ai = mfma16(A, Bi[kk], ai);
        au = mfma16(A, Bu[kk], au);
        ao = mfma16(A, Bo[kk], ao);
      }
      #pragma unroll
      for (int j = 0; j < 4; ++j){
        const int m = mt * 16 + (lane >> 4) * 4 + j;
        const float ig = sigm(ai[j] + bi), ug = ftanh(au[j] + bu), og = sigm(ao[j] + bo);
        const float cc = ig * ug, hh = og * ftanh(cc);
        const size_t o = (size_t)(row0 + m) * DIM + e;
        bc[o] = f2bf(cc); bh[o] = f2bf(hh);
      }
    }
  }
}

// ---------------- K2: tree scan with LDS-resident stacks ----------------
// 32 blocks x 512 threads; 16 batch rows per block. Stacks never touch global.
#define LSLOTS 4
#define HSLOT  4224           // 16 rows * 264 elems per slot
__global__ __launch_bounds__(512) void k2_tree(
    const int* __restrict__ ops,
    const unsigned short* __restrict__ bh, const unsigned short* __restrict__ bc,
    const unsigned short* __restrict__ Ui, const unsigned short* __restrict__ Uf,
    const unsigned short* __restrict__ Uo, const unsigned short* __restrict__ Uu,
    const float* __restrict__ Uib, const float* __restrict__ Ufb,
    const float* __restrict__ Uob, const float* __restrict__ Uub,
    float* __restrict__ r_vec)
{
  __shared__ unsigned short hstk[LSLOTS * HSLOT];   // 33,792 B  bf16 h stack
  __shared__ float          cstk[LSLOTS * HSLOT];   // 67,584 B  fp32 c stack
  __shared__ unsigned short HSb[HSLOT];             //  8,448 B  h1+h2 (GEMM A)
  __shared__ float          rtop[HSLOT];            // 16,896 B  fp32 top-of-stack h
  __shared__ int opm[16], ptrv[16], lidxA[16], ridxA[16];

  const int tid = threadIdx.x;
  const int lane = tid & 63, wv = tid >> 6;          // wv in [0,8)
  const int lr = lane & 15, lk = (lane >> 4) * 8;
  const int rb = blockIdx.x * 16;

  // zero-init LDS state
  for (int i = tid; i < LSLOTS * HSLOT / 8; i += 512) ((uint4*)hstk)[i] = uint4{0,0,0,0};
  for (int i = tid; i < LSLOTS * HSLOT / 4; i += 512) ((uint4*)cstk)[i] = uint4{0,0,0,0};
  for (int i = tid; i < HSLOT / 8;          i += 512) ((uint4*)HSb)[i]  = uint4{0,0,0,0};
  for (int i = tid; i < HSLOT / 4;          i += 512) ((uint4*)rtop)[i] = uint4{0,0,0,0};
  if (tid < 16) ptrv[tid] = 0;

  // per-thread bias / e-offset preload (e fixed per thread per et)
  float bI[2], bO[2], bU[2], bF[2];
  int eo[2];
  #pragma unroll
  for (int et = 0; et < 2; ++et){
    const int e = wv * 32 + et * 16 + lr;
    eo[et] = e; bI[et] = Uib[e]; bO[et] = Uob[e]; bU[et] = Uub[e]; bF[et] = Ufb[e];
  }

  // push-column prefetch (thread owns row pm, 8 elems at pc)
  const int pm = tid >> 5, pc = (tid & 31) * 8;
  bf16x8_t ph  = *(const bf16x8_t*)(bh + ((size_t)(rb + pm) * SEQ + 0) * DIM + pc);
  bf16x8_t pcv = *(const bf16x8_t*)(bc + ((size_t)(rb + pm) * SEQ + 0) * DIM + pc);

  __syncthreads();

  for (int s = 0; s < SEQ; ++s){
    if (tid < 16){
      opm[tid] = ops[(size_t)(rb + tid) * SEQ + s];
      const int p = ptrv[tid];
      lidxA[tid] = (p - 2 > 0) ? (p - 2) : 0;
      ridxA[tid] = (p - 1 > 0) ? (p - 1) : 0;
    }
    __syncthreads();                                   // sync1
    bool anyred = false, anypush = false;
    #pragma unroll
    for (int m = 0; m < 16; ++m){ const int o = opm[m]; anyred |= (o == 1); anypush |= (o == 0); }

    // ---- phase B: push writes + HS build (LDS only) ----
    if (anypush && opm[pm] == 0){
      const int ps = (ptrv[pm] < LSLOTS - 1) ? ptrv[pm] : (LSLOTS - 1);
      *(bf16x8_t*)(hstk + ps * HSLOT + pm * 264 + pc) = ph;
      float cf[8];
      #pragma unroll
      for (int i = 0; i < 8; ++i) cf[i] = bf2f((unsigned short)pcv[i]);
      float* cd = cstk + ps * HSLOT + pm * 264 + pc;
      *(float4*)(cd)     = float4{cf[0], cf[1], cf[2], cf[3]};
      *(float4*)(cd + 4) = float4{cf[4], cf[5], cf[6], cf[7]};
      float* rd = rtop + pm * 264 + pc;
      #pragma unroll
      for (int i = 0; i < 8; ++i) rd[i] = bf2f((unsigned short)ph[i]);
    }
    if (anyred && opm[pm] == 1){
      const int sl = lidxA[pm], sr = ridxA[pm];
      bf16x8_t a8 = *(const bf16x8_t*)(hstk + sl * HSLOT + pm * 264 + pc);
      bf16x8_t b8 = *(const bf16x8_t*)(hstk + sr * HSLOT + pm * 264 + pc);
      unsigned int* hd = (unsigned int*)(HSb + pm * 264 + pc);
      #pragma unroll
      for (int i = 0; i < 4; ++i){
        const float s0 = bf2f((unsigned short)a8[2*i])   + bf2f((unsigned short)b8[2*i]);
        const float s1 = bf2f((unsigned short)a8[2*i+1]) + bf2f((unsigned short)b8[2*i+1]);
        hd[i] = bfpack(s0, s1);
      }
    }
    // prefetch next push column (overlaps with GEMM below)
    if (s + 1 < SEQ){
      ph  = *(const bf16x8_t*)(bh + ((size_t)(rb + pm) * SEQ + (s + 1)) * DIM + pc);
      pcv = *(const bf16x8_t*)(bc + ((size_t)(rb + pm) * SEQ + (s + 1)) * DIM + pc);
    }

    if (anyred){
      __syncthreads();                                 // sync2: HS ready
      // ---- phase C: 5 GEMMs (K=256), weights streamed from L2 ----
      float hnv[2][4], cnv[2][4];
      const int sl1 = lidxA[lr], sl2 = ridxA[lr];
      const unsigned short* pS = HSb + lr * 264 + lk;
      const unsigned short* p1 = hstk + sl1 * HSLOT + lr * 264 + lk;
      const unsigned short* p2 = hstk + sl2 * HSLOT + lr * 264 + lk;
      #pragma unroll
      for (int et = 0; et < 2; ++et){
        const int e = eo[et];
        const size_t wb = (size_t)e * DIM + lk;
        f32x4_t ai = {0,0,0,0}, ao = {0,0,0,0}, au = {0,0,0,0}, a1 = {0,0,0,0}, a2 = {0,0,0,0};
        #pragma unroll
        for (int kk = 0; kk < 8; ++kk){
          bf16x8_t AS = *(const bf16x8_t*)(pS + kk * 32);
          bf16x8_t A1 = *(const bf16x8_t*)(p1 + kk * 32);
          bf16x8_t A2 = *(const bf16x8_t*)(p2 + kk * 32);
          bf16x8_t Wi_ = *(const bf16x8_t*)(Ui + wb + kk * 32);
          bf16x8_t Wo_ = *(const bf16x8_t*)(Uo + wb + kk * 32);
          bf16x8_t Wu_ = *(const bf16x8_t*)(Uu + wb + kk * 32);
          bf16x8_t Wf_ = *(const bf16x8_t*)(Uf + wb + kk * 32);
          ai = mfma16(AS, Wi_, ai);
          ao = mfma16(AS, Wo_, ao);
          au = mfma16(AS, Wu_, au);
          a1 = mfma16(A1, Wf_, a1);
          a2 = mfma16(A2, Wf_, a2);
        }
        #pragma unroll
        for (int j = 0; j < 4; ++j){
          const int m = (lane >> 4) * 4 + j;
          const float ig = sigm(ai[j] + bI[et]), og = sigm(ao[j] + bO[et]), ug = ftanh(au[j] + bU[et]);
          const float f1 = sigm(a1[j] + bF[et]), f2 = sigm(a2[j] + bF[et]);
          const float c1 = cstk[lidxA[m] * HSLOT + m * 264 + e];
          const float c2 = cstk[ridxA[m] * HSLOT + m * 264 + e];
          const float cn = ig * ug + f1 * c1 + f2 * c2;
          cnv[et][j] = cn;
          hnv[et][j] = og * ftanh(cn);
        }
      }
      __syncthreads();                                 // sync3: GEMM reads done
      // ---- phase D: reduce writes + ptr update ----
      #pragma unroll
      for (int et = 0; et < 2; ++et){
        #pragma unroll
        for (int j = 0; j < 4; ++j){
          const int m = (lane >> 4) * 4 + j;
          if (opm[m] == 1){
            const int sl = lidxA[m];
            hstk[sl * HSLOT + m * 264 + eo[et]] = f2bf(hnv[et][j]);
            cstk[sl * HSLOT + m * 264 + eo[et]] = cnv[et][j];
            rtop[m * 264 + eo[et]] = hnv[et][j];
          }
        }
      }
      if (tid < 16){
        const int o = opm[tid];
        ptrv[tid] += (o == 0) ? 1 : ((o == 1) ? -1 : 0);
      }
      __syncthreads();   // sync4: phase D reads of opm/lidxA done before next-step overwrite
    } else {
      __syncthreads();                                 // syncE (push/pad-only step)
      if (tid < 16){
        const int o = opm[tid];
        ptrv[tid] += (o == 0) ? 1 : ((o == 1) ? -1 : 0);
      }
    }
  }
  __syncthreads();
  // final root h = rtop (fp32, exact top-of-stack)
  {
    const float* rs = rtop + pm * 264 + pc;
    float* dst = r_vec + (size_t)(rb + pm) * DIM + pc;
    *(float4*)(dst)     = *(const float4*)(rs);
    *(float4*)(dst + 4) = *(const float4*)(rs + 4);
  }
}

// ---------------- K34: fused vv projection + attention + FC1 (per batch item) ----------------
__global__ __launch_bounds__(256) void k34_attn(
    const float* __restrict__ v, const unsigned short* __restrict__ Wwbf,
    const float* __restrict__ W_b, const float* __restrict__ r_vec,
    const unsigned short* __restrict__ WQbf, const float* __restrict__ WQb,
    const unsigned short* __restrict__ WVbf, const float* __restrict__ WPw,
    const unsigned short* __restrict__ FC1bf, const float* __restrict__ FC1b,
    float* __restrict__ z)
{
  __shared__ unsigned short vvt[196 * 264];     // 103,488 B  bf16 vv tile
  __shared__ char sun[16896];                   // union: vstage [16][520] u16 / pre [16][264] f32
  __shared__ float scv[216];
  __shared__ float wqv[256];
  __shared__ float rld[256];
  __shared__ float attv[256];
  __shared__ float wpld[256];
  __shared__ float red[8];
  unsigned short* vstage = (unsigned short*)sun;
  float* pre = (float*)sun;

  const int b = blockIdx.x, tid = threadIdx.x;
  const int lane = tid & 63, wv = tid >> 6;
  const int lr = lane & 15, lk = (lane >> 4) * 8;

  rld[tid]  = r_vec[(size_t)b * DIM + tid];
  wpld[tid] = WPw[tid];

  // cache W_w fragments in VGPRs (one-time 256 KB stream per block)
  bf16x8_t Aw[4][16];
  float wbias[4];
  #pragma unroll
  for (int et = 0; et < 4; ++et){
    const int e = et * 64 + wv * 16 + lr;
    wbias[et] = W_b[e];
    const size_t wb = (size_t)e * VDIM + lk;
    #pragma unroll
    for (int kk = 0; kk < 16; ++kk) Aw[et][kk] = *(const bf16x8_t*)(Wwbf + wb + kk * 32);
  }
  __syncthreads();
  // wqq = r @ WQ^T + b (scalar matvec, one output per thread)
  {
    float acc = WQb[tid];
    const unsigned short* wr = WQbf + (size_t)tid * DIM;
    for (int d = 0; d < DIM; d += 8){
      uint4 w4 = *(const uint4*)(wr + d);
      float a0,a1,a2,a3,a4,a5,a6,a7;
      bf2x(w4.x,a0,a1); bf2x(w4.y,a2,a3); bf2x(w4.z,a4,a5); bf2x(w4.w,a6,a7);
      acc += a0*rld[d] + a1*rld[d+1] + a2*rld[d+2] + a3*rld[d+3]
           + a4*rld[d+4] + a5*rld[d+5] + a6*rld[d+6] + a7*rld[d+7];
    }
    wqv[tid] = acc;
  }
  // ---- phase A: vvt = tanh(v[b] @ W_w^T + W_b), 16-row tiles ----
  for (int t = 0; t < 13; ++t){
    const int r0 = t * 16;
    __syncthreads();                       // protect vstage reuse
    {
      const int m = tid >> 4, c = (tid & 15) * 32;
      const int gr = r0 + m;
      if (gr < RREG){
        const float* src = v + ((size_t)b * RREG + gr) * VDIM + c;
        #pragma unroll
        for (int k = 0; k < 32; k += 4){
          float4 x = *(const float4*)(src + k);
          *(unsigned int*)&vstage[m * 520 + c + k]     = bfpack(x.x, x.y);
          *(unsigned int*)&vstage[m * 520 + c + k + 2] = bfpack(x.z, x.w);
        }
      }
    }
    __syncthreads();
    #pragma unroll
    for (int et = 0; et < 4; ++et){
      const int e = et * 64 + wv * 16 + lr;
      f32x4_t acc = {0,0,0,0};
      const unsigned short* ar = vstage + lr * 520 + lk;
      #pragma unroll
      for (int kk = 0; kk < 16; ++kk)
        acc = mfma16(*(const bf16x8_t*)(ar + kk * 32), Aw[et][kk], acc);
      #pragma unroll
      for (int j = 0; j < 4; ++j){
        const int gr = r0 + (lane >> 4) * 4 + j;
        if (gr < RREG) vvt[gr * 264 + e] = f2bf(ftanh(acc[j] + wbias[et]));
      }
    }
  }
  // cache WV fragments in VGPRs for phase B (after Aw's last use)
  bf16x8_t Bv[4][8];
  #pragma unroll
  for (int et = 0; et < 4; ++et){
    const int e = et * 64 + wv * 16 + lr;
    const size_t wb = (size_t)e * DIM + lk;
    #pragma unroll
    for (int kk = 0; kk < 8; ++kk) Bv[et][kk] = *(const bf16x8_t*)(WVbf + wb + kk * 32);
  }
  __syncthreads();
  // ---- phase B: scores ----
  for (int t = 0; t < 13; ++t){
    const int arow = t * 16 + lr;
    const unsigned short* ar = vvt + ((arow < RREG) ? arow : (RREG - 1)) * 264 + lk;
    #pragma unroll
    for (int et = 0; et < 4; ++et){
      const int e = et * 64 + wv * 16 + lr;
      f32x4_t acc = {0,0,0,0};
      #pragma unroll
      for (int kk = 0; kk < 8; ++kk)
        acc = mfma16(*(const bf16x8_t*)(ar + kk * 32), Bv[et][kk], acc);
      const float wqe = wqv[e];
      #pragma unroll
      for (int j = 0; j < 4; ++j){
        const int m = (lane >> 4) * 4 + j;
        pre[m * 264 + e] = ftanh(acc[j] + wqe);
      }
    }
    __syncthreads();
    {
      const int m = tid >> 4, cc = (tid & 15) * 16;
      float p_ = 0.f;
      #pragma unroll
      for (int k = 0; k < 16; ++k) p_ += pre[m * 264 + cc + k] * wpld[cc + k];
      #pragma unroll
      for (int off = 8; off; off >>= 1) p_ += __shfl_xor(p_, off, 16);
      if ((tid & 15) == 0){
        const int rr = t * 16 + m;
        scv[rr] = (rr < RREG) ? p_ : -1e30f;
      }
    }
    __syncthreads();
  }
  // ---- softmax over 196 ----
  {
    const float sv = (tid < RREG) ? scv[tid] : -1e30f;
    float m_ = sv;
    #pragma unroll
    for (int off = 32; off; off >>= 1) m_ = fmaxf(m_, __shfl_xor(m_, off, 64));
    if (lane == 0) red[wv] = m_;
    __syncthreads();
    m_ = fmaxf(fmaxf(red[0], red[1]), fmaxf(red[2], red[3]));
    const float ex = (tid < RREG) ? __expf(sv - m_) : 0.f;
    float s_ = ex;
    #pragma unroll
    for (int off = 32; off; off >>= 1) s_ += __shfl_xor(s_, off, 64);
    if (lane == 0) red[4 + wv] = s_;
    __syncthreads();
    s_ = red[4] + red[5] + red[6] + red[7];
    if (tid < RREG) scv[tid] = ex / s_;
  }
  __syncthreads();
  // ---- att = p . vv + r (vv from LDS) ----
  {
    float a = rld[tid];
    #pragma unroll 4
    for (int rr = 0; rr < RREG; ++rr) a += scv[rr] * bf2f(vvt[rr * 264 + tid]);
    attv[tid] = a;
  }
  __syncthreads();
  // ---- z = tanh(att @ FC1^T + b) ----
  {
    float acc = FC1b[tid];
    const unsigned short* wr = FC1bf + (size_t)tid * DIM;
    for (int d = 0; d < DIM; d += 8){
      uint4 w4 = *(const uint4*)(wr + d);
      float a0,a1,a2,a3,a4,a5,a6,a7;
      bf2x(w4.x,a0,a1); bf2x(w4.y,a2,a3); bf2x(w4.z,a4,a5); bf2x(w4.w,a6,a7);
      acc += a0*attv[d] + a1*attv[d+1] + a2*attv[d+2] + a3*attv[d+3]
           + a4*attv[d+4] + a5*attv[d+5] + a6*attv[d+6] + a7*attv[d+7];
    }
    z[(size_t)b * DIM + tid] = ftanh(acc);
  }
}

// ---------------- K5: FC2 ----------------
__global__ __launch_bounds__(256) void k5_fc2(
    const float* __restrict__ z, const unsigned short* __restrict__ FC2bf,
    const float* __restrict__ FC2b, float* __restrict__ out)
{
  __shared__ unsigned short zt[16][264];
  const int tid = threadIdx.x;
  const int rb = blockIdx.x * 16, ob = blockIdx.y * 64;
  {
    const int m = tid >> 4, c = (tid & 15) * 16;
    const float* src = z + (size_t)(rb + m) * DIM + c;
    #pragma unroll
    for (int k = 0; k < 16; k += 4){
      float4 x = *(const float4*)(src + k);
      *(unsigned int*)&zt[m][c + k]     = bfpack(x.x, x.y);
      *(unsigned int*)&zt[m][c + k + 2] = bfpack(x.z, x.w);
    }
  }
  __syncthreads();
  const int lane = tid & 63, wv = tid >> 6;
  const int lr = lane & 15, lk = (lane >> 4) * 8;
  const int o = ob + wv * 16 + lr;
  f32x4_t acc = {0,0,0,0};
  const size_t wb = (size_t)o * DIM + lk;
  const unsigned short* ar = &zt[lr][lk];
  #pragma unroll
  for (int kk = 0; kk < 8; ++kk){
    bf16x8_t A = *(const bf16x8_t*)(ar + kk * 32);
    bf16x8_t Bb = *(const bf16x8_t*)(FC2bf + wb + kk * 32);
    acc = mfma16(A, Bb, acc);
  }
  if (o < NOUTP){
    const float bo = FC2b[o];
    #pragma unroll
    for (int j = 0; j < 4; ++j){
      const int m = (lane >> 4) * 4 + j;
      out[(size_t)(rb + m) * NOUTP + o] = acc[j] + bo;
    }
  }
}

// ---------------- launch ----------------
extern "C" void kernel_launch(void* const* d_in, const int* in_sizes, int n_in,
                              void* d_out, int out_size, void* d_ws, size_t ws_size,
                              hipStream_t stream) {
  const float* v         = (const float*)d_in[0];
  const int*   questions = (const int*)d_in[1];
  const int*   ops       = (const int*)d_in[2];
  const float* wembed    = (const float*)d_in[4];
  const float* W_w  = (const float*)d_in[5];   const float* W_b  = (const float*)d_in[6];
  const float* Wi_w = (const float*)d_in[7];   const float* Wi_b = (const float*)d_in[8];
  const float* Wu_w = (const float*)d_in[9];   const float* Wu_b = (const float*)d_in[10];
  const float* Wo_w = (const float*)d_in[11];  const float* Wo_b = (const float*)d_in[12];
  const float* Ui_w = (const float*)d_in[13];  const float* Ui_b = (const float*)d_in[14];
  const float* Uf_w = (const float*)d_in[15];  const float* Uf_b = (const float*)d_in[16];
  const float* Uo_w = (const float*)d_in[17];  const float* Uo_b = (const float*)d_in[18];
  const float* Uu_w = (const float*)d_in[19];  const float* Uu_b = (const float*)d_in[20];
  const float* WQ_w = (const float*)d_in[21];  const float* WQ_b = (const float*)d_in[22];
  const float* WV_w = (const float*)d_in[23];
  const float* WP_w = (const float*)d_in[24];
  const float* FC1_w = (const float*)d_in[26]; const float* FC1_b = (const float*)d_in[27];
  const float* FC2_w = (const float*)d_in[28]; const float* FC2_b = (const float*)d_in[29];
  float* out = (float*)d_out;
  char* ws = (char*)d_ws;

  unsigned short* Wwbf  = (unsigned short*)(ws + OFF_WWBF);
  unsigned short* Wibf  = (unsigned short*)(ws + OFF_WIBF);
  unsigned short* Wubf  = (unsigned short*)(ws + OFF_WUBF);
  unsigned short* Wobf  = (unsigned short*)(ws + OFF_WOBF);
  unsigned short* Uibf  = (unsigned short*)(ws + OFF_UIBF);
  unsigned short* Ufbf  = (unsigned short*)(ws + OFF_UFBF);
  unsigned short* Uobf  = (unsigned short*)(ws + OFF_UOBF);
  unsigned short* Uubf  = (unsigned short*)(ws + OFF_UUBF);
  unsigned short* WVbf  = (unsigned short*)(ws + OFF_WVBF);
  unsigned short* WQbf  = (unsigned short*)(ws + OFF_WQBF);
  unsigned short* FC1bf = (unsigned short*)(ws + OFF_FC1BF);
  unsigned short* FC2bf = (unsigned short*)(ws + OFF_FC2BF);
  float* r_vec = (float*)(ws + OFF_RVEC);
  float* z     = (float*)(ws + OFF_Z);
  unsigned short* bh = (unsigned short*)(ws + OFF_BH);
  unsigned short* bc = (unsigned short*)(ws + OFF_BC);

  ConvArgs ca;
  const float* srcs[13] = { W_w, Wi_w, Wu_w, Wo_w, Ui_w, Uf_w, Uo_w, Uu_w, WV_w, WQ_w, FC1_w, FC2_w, nullptr };
  unsigned short* dsts[13] = { Wwbf, Wibf, Wubf, Wobf, Uibf, Ufbf, Uobf, Uubf, WVbf, WQbf, FC1bf, FC2bf, FC2bf + 768000 };
  int ns[13] = { 131072, 65536, 65536, 65536, 65536, 65536, 65536, 65536, 65536, 65536, 65536, 768000, 2048 };
  for (int i = 0; i < 13; ++i){ ca.src[i] = srcs[i]; ca.dst[i] = dsts[i]; ca.n[i] = ns[i]; }
  k0_convert<<<512, 256, 0, stream>>>(ca);

  k1_leaf<<<504, 256, 0, stream>>>(questions, wembed, Wibf, Wubf, Wobf, Wi_b, Wu_b, Wo_b, bh, bc);

  k2_tree<<<32, 512, 0, stream>>>(ops, bh, bc, Uibf, Ufbf, Uobf, Uubf,
                                  Ui_b, Uf_b, Uo_b, Uu_b, r_vec);

  k34_attn<<<512, 256, 0, stream>>>(v, Wwbf, W_b, r_vec, WQbf, WQ_b, WVbf, WP_w,
                                    FC1bf, FC1_b, z);

  k5_fc2<<<dim3(32, 47), 256, 0, stream>>>(z, FC2bf, FC2_b, out);

  (void)in_sizes; (void)n_in; (void)out_size; (void)ws_size;
}

// Round 6
// 1076.330 us; speedup vs baseline: 1.2588x; 1.0473x over previous
//
#include <hip/hip_runtime.h>
#include <hip/hip_bf16.h>

#define BSZ   512
#define SEQ   63
#define DIM   256
#define VDIM  512
#define RREG  196
#define NOUTP 3000

using f32x4_t  = __attribute__((ext_vector_type(4))) float;
using bf16x8_t = __attribute__((ext_vector_type(8))) short;
using u16x4_t  = __attribute__((ext_vector_type(4))) unsigned short;

__device__ inline float bf2f(unsigned short u){
  union { unsigned int i; float f; } x; x.i = ((unsigned int)u) << 16; return x.f;
}
__device__ inline unsigned short f2bf(float f){
  unsigned int u = __float_as_uint(f);
  unsigned int r = (u + 0x7fffu + ((u >> 16) & 1u)) >> 16;   // RNE
  return (unsigned short)r;
}
__device__ inline unsigned int bfpack(float a, float b){
  return (unsigned int)f2bf(a) | ((unsigned int)f2bf(b) << 16);
}
__device__ inline void bf2x(unsigned int w, float& a, float& b){
  union { unsigned int i; float f; } x, y;
  x.i = w << 16; y.i = w & 0xffff0000u; a = x.f; b = y.f;
}
__device__ inline float sigm(float x){ return 1.f / (1.f + __expf(-x)); }
__device__ inline float ftanh(float x){ return 1.f - 2.f / (__expf(2.f * x) + 1.f); }

__device__ inline f32x4_t mfma16(bf16x8_t a, bf16x8_t b, f32x4_t c){
  return __builtin_amdgcn_mfma_f32_16x16x32_bf16(a, b, c, 0, 0, 0);
}

// ---------------- workspace layout (bytes) -- total 37,191,680 ----------------
#define OFF_WWBF   0u
#define OFF_WIBF   262144u
#define OFF_WUBF   393216u
#define OFF_WOBF   524288u
#define OFF_UIBF   655360u
#define OFF_UFBF   786432u
#define OFF_UOBF   917504u
#define OFF_UUBF   1048576u
#define OFF_WVBF   1179648u
#define OFF_WQBF   1310720u
#define OFF_FC1BF  1441792u
#define OFF_FC2BF  1572864u
#define OFF_RVEC   3112960u
#define OFF_Z      3637248u
#define OFF_BH     4161536u
#define OFF_BC     20676608u

// ---------------- K0: fp32 -> bf16 weight conversion ----------------
struct ConvArgs {
  const float* src[13];
  unsigned short* dst[13];
  int n[13];
};

__global__ __launch_bounds__(256) void k0_convert(ConvArgs a){
  const int gid = blockIdx.x * 256 + threadIdx.x;
  const int stride = gridDim.x * 256;
  #pragma unroll 1
  for (int j = 0; j < 13; ++j){
    const float* s = a.src[j];
    unsigned short* d = a.dst[j];
    const int n = a.n[j];
    if (s){
      for (int i = gid; i < n; i += stride) d[i] = f2bf(s[i]);
    } else {
      for (int i = gid; i < n; i += stride) d[i] = 0;
    }
  }
}

// ---------------- K1: leaf gates (bh, bc) ----------------
__global__ __launch_bounds__(256) void k1_leaf(
    const int* __restrict__ questions, const float* __restrict__ wembed,
    const unsigned short* __restrict__ Wi, const unsigned short* __restrict__ Wu,
    const unsigned short* __restrict__ Wo,
    const float* __restrict__ Wib, const float* __restrict__ Wub, const float* __restrict__ Wob,
    unsigned short* __restrict__ bh, unsigned short* __restrict__ bc)
{
  __shared__ unsigned short qt[64][264];
  __shared__ int qidx[64];
  const int tid = threadIdx.x;
  const int row0 = blockIdx.x * 64;
  if (tid < 64) qidx[tid] = questions[row0 + tid];
  __syncthreads();
  {
    const int mb = tid >> 4, c = (tid & 15) * 16;
    #pragma unroll
    for (int rr = 0; rr < 4; ++rr){
      const int m = mb + rr * 16;
      const float* src = wembed + (size_t)qidx[m] * DIM + c;
      #pragma unroll
      for (int k = 0; k < 16; k += 4){
        float4 x = *(const float4*)(src + k);
        *(unsigned int*)&qt[m][c + k]     = bfpack(x.x, x.y);
        *(unsigned int*)&qt[m][c + k + 2] = bfpack(x.z, x.w);
      }
    }
  }
  __syncthreads();
  const int lane = tid & 63, wv = tid >> 6;
  const int lr = lane & 15, lk = (lane >> 4) * 8;
  for (int et = 0; et < 4; ++et){
    const int e = et * 64 + wv * 16 + lr;
    bf16x8_t Bi[8], Bu[8], Bo[8];
    const size_t wb = (size_t)e * DIM + lk;
    #pragma unroll
    for (int kk = 0; kk < 8; ++kk){
      Bi[kk] = *(const bf16x8_t*)(Wi + wb + kk * 32);
      Bu[kk] = *(const bf16x8_t*)(Wu + wb + kk * 32);
      Bo[kk] = *(const bf16x8_t*)(Wo + wb + kk * 32);
    }
    const float bi = Wib[e], bu = Wub[e], bo = Wob[e];
    for (int mt = 0; mt < 4; ++mt){
      f32x4_t ai = {0,0,0,0}, au = {0,0,0,0}, ao = {0,0,0,0};
      const unsigned short* ar = &qt[mt * 16 + lr][lk];
      #pragma unroll
      for (int kk = 0; kk < 8; ++kk){
        bf16x8_t A = *(const bf16x8_t*)(ar + kk * 32);
        ai = mfma16(A, Bi[kk], ai);
        au = mfma16(A, Bu[kk], au);
        ao = mfma16(A, Bo[kk], ao);
      }
      #pragma unroll
      for (int j = 0; j < 4; ++j){
        const int m = mt * 16 + (lane >> 4) * 4 + j;
        const float ig = sigm(ai[j] + bi), ug = ftanh(au[j] + bu), og = sigm(ao[j] + bo);
        const float cc = ig * ug, hh = og * ftanh(cc);
        const size_t o = (size_t)(row0 + m) * DIM + e;
        bc[o] = f2bf(cc); bh[o] = f2bf(hh);
      }
    }
  }
}

// ---------------- K2: tree scan, 1024 threads, precomputed schedule ----------------
// 32 blocks x 1024 threads; 16 batch rows per block; wave w owns e-slice [w*16, w*16+16)
// and (for phase B) batch row w. Stacks LDS-resident. 3 barriers per reduce step, 0 per push.
#define LSLOTS 4
#define HSLOT  4224           // 16 rows * 264 elems per slot
__global__ __launch_bounds__(1024, 4) void k2_tree(
    const int* __restrict__ ops,
    const unsigned short* __restrict__ bh, const unsigned short* __restrict__ bc,
    const unsigned short* __restrict__ Ui, const unsigned short* __restrict__ Uf,
    const unsigned short* __restrict__ Uo, const unsigned short* __restrict__ Uu,
    const float* __restrict__ Uib, const float* __restrict__ Ufb,
    const float* __restrict__ Uob, const float* __restrict__ Uub,
    float* __restrict__ r_vec)
{
  __shared__ unsigned short hstk[LSLOTS * HSLOT];   // 33,792 B
  __shared__ float          cstk[LSLOTS * HSLOT];   // 67,584 B
  __shared__ unsigned short HSb[HSLOT];             //  8,448 B
  __shared__ float          rtop[HSLOT];            // 16,896 B
  __shared__ unsigned char stOp[SEQ][16], stL[SEQ][16], stR[SEQ][16], stW[SEQ][16];
  __shared__ unsigned char stRed[SEQ];

  const int tid = threadIdx.x;
  const int lane = tid & 63;
  const int wv = tid >> 6;            // 0..15
  const int lr = lane & 15, lk = (lane >> 4) * 8;
  const int rb = blockIdx.x * 16;
  const int e  = wv * 16 + lr;        // this thread's output column
  const int pm = wv;                  // batch row owned for push/HS build
  const int pc = lane * 4;            // 4 elems (8 B) per lane

  // zero-init LDS state
  for (int i = tid; i < LSLOTS * HSLOT / 8; i += 1024) ((uint4*)hstk)[i] = uint4{0,0,0,0};
  for (int i = tid; i < LSLOTS * HSLOT / 4; i += 1024) ((uint4*)cstk)[i] = uint4{0,0,0,0};
  for (int i = tid; i < HSLOT / 8;          i += 1024) ((uint4*)HSb)[i]  = uint4{0,0,0,0};
  for (int i = tid; i < HSLOT / 4;          i += 1024) ((uint4*)rtop)[i] = uint4{0,0,0,0};
  // parallel ops load
  if (tid < SEQ * 16){
    const int m = tid & 15, s = tid >> 4;
    stOp[s][m] = (unsigned char)ops[(size_t)(rb + m) * SEQ + s];
  }
  __syncthreads();
  // precompute per-step stack schedule (one short serial walk, once)
  if (tid < 16){
    int p = 0;
    for (int s = 0; s < SEQ; ++s){
      const int o = stOp[s][tid];
      const int l = (p - 2 > 0) ? (p - 2) : 0;
      const int r = (p - 1 > 0) ? (p - 1) : 0;
      stL[s][tid] = (unsigned char)l;
      stR[s][tid] = (unsigned char)r;
      stW[s][tid] = (unsigned char)((o == 0) ? ((p < LSLOTS - 1) ? p : (LSLOTS - 1)) : l);
      p += (o == 0) ? 1 : ((o == 1) ? -1 : 0);
    }
  } else if (tid >= 64 && tid < 64 + SEQ){
    const int s = tid - 64;
    int any = 0;
    #pragma unroll
    for (int m = 0; m < 16; ++m) any |= (stOp[s][m] == 1) ? 1 : 0;
    stRed[s] = (unsigned char)any;
  }

  const float bI = Uib[e], bO = Uob[e], bU = Uub[e], bF = Ufb[e];
  // push-column prefetch (wave pm loads its row: 64 lanes x 8 B contiguous)
  u16x4_t ph  = *(const u16x4_t*)(bh + ((size_t)(rb + pm) * SEQ + 0) * DIM + pc);
  u16x4_t pcv = *(const u16x4_t*)(bc + ((size_t)(rb + pm) * SEQ + 0) * DIM + pc);
  __syncthreads();

  for (int s = 0; s < SEQ; ++s){
    const int myop = stOp[s][pm];
    // ---- phase B (per-row by wave; no cross-wave hazards) ----
    if (myop == 0){
      const int ps = stW[s][pm];
      *(u16x4_t*)(hstk + ps * HSLOT + pm * 264 + pc) = ph;
      float4 cf = { bf2f((unsigned short)pcv[0]), bf2f((unsigned short)pcv[1]),
                    bf2f((unsigned short)pcv[2]), bf2f((unsigned short)pcv[3]) };
      *(float4*)(cstk + ps * HSLOT + pm * 264 + pc) = cf;
      float4 hf = { bf2f((unsigned short)ph[0]), bf2f((unsigned short)ph[1]),
                    bf2f((unsigned short)ph[2]), bf2f((unsigned short)ph[3]) };
      *(float4*)(rtop + pm * 264 + pc) = hf;
    } else {
      const int sl = stL[s][pm], sr = stR[s][pm];
      u16x4_t a4 = *(const u16x4_t*)(hstk + sl * HSLOT + pm * 264 + pc);
      u16x4_t b4 = *(const u16x4_t*)(hstk + sr * HSLOT + pm * 264 + pc);
      u16x4_t o4;
      #pragma unroll
      for (int i = 0; i < 4; ++i)
        o4[i] = f2bf(bf2f((unsigned short)a4[i]) + bf2f((unsigned short)b4[i]));
      *(u16x4_t*)(HSb + pm * 264 + pc) = o4;
    }
    // prefetch next push column (hidden under phase C)
    if (s + 1 < SEQ){
      ph  = *(const u16x4_t*)(bh + ((size_t)(rb + pm) * SEQ + (s + 1)) * DIM + pc);
      pcv = *(const u16x4_t*)(bc + ((size_t)(rb + pm) * SEQ + (s + 1)) * DIM + pc);
    }

    if (stRed[s]){
      __syncthreads();                       // bar1: all B writes (and prev D) visible
      // ---- phase C: 5 GEMMs, weights batched 8 loads at a time ----
      const int sl1 = stL[s][lr], sl2 = stR[s][lr];
      const unsigned short* p1 = hstk + sl1 * HSLOT + lr * 264 + lk;
      const unsigned short* p2 = hstk + sl2 * HSLOT + lr * 264 + lk;
      const unsigned short* pS = HSb + lr * 264 + lk;
      bf16x8_t AS[8];
      #pragma unroll
      for (int kk = 0; kk < 8; ++kk) AS[kk] = *(const bf16x8_t*)(pS + kk * 32);
      const size_t wb = (size_t)e * DIM + lk;
      f32x4_t ai = {0,0,0,0}, ao = {0,0,0,0}, au = {0,0,0,0}, a1 = {0,0,0,0}, a2 = {0,0,0,0};
      {
        bf16x8_t wf[8];
        #pragma unroll
        for (int kk = 0; kk < 8; ++kk) wf[kk] = *(const bf16x8_t*)(Ui + wb + kk * 32);
        #pragma unroll
        for (int kk = 0; kk < 8; ++kk) ai = mfma16(AS[kk], wf[kk], ai);
        #pragma unroll
        for (int kk = 0; kk < 8; ++kk) wf[kk] = *(const bf16x8_t*)(Uo + wb + kk * 32);
        #pragma unroll
        for (int kk = 0; kk < 8; ++kk) ao = mfma16(AS[kk], wf[kk], ao);
        #pragma unroll
        for (int kk = 0; kk < 8; ++kk) wf[kk] = *(const bf16x8_t*)(Uu + wb + kk * 32);
        #pragma unroll
        for (int kk = 0; kk < 8; ++kk) au = mfma16(AS[kk], wf[kk], au);
        #pragma unroll
        for (int kk = 0; kk < 8; ++kk) wf[kk] = *(const bf16x8_t*)(Uf + wb + kk * 32);
        #pragma unroll
        for (int kk = 0; kk < 8; ++kk){
          a1 = mfma16(*(const bf16x8_t*)(p1 + kk * 32), wf[kk], a1);
          a2 = mfma16(*(const bf16x8_t*)(p2 + kk * 32), wf[kk], a2);
        }
      }
      float hn[4], cn[4];
      #pragma unroll
      for (int j = 0; j < 4; ++j){
        const int m = (lane >> 4) * 4 + j;
        const float ig = sigm(ai[j] + bI), og = sigm(ao[j] + bO), ug = ftanh(au[j] + bU);
        const float f1 = sigm(a1[j] + bF), f2 = sigm(a2[j] + bF);
        const float c1 = cstk[(int)stL[s][m] * HSLOT + m * 264 + e];
        const float c2 = cstk[(int)stR[s][m] * HSLOT + m * 264 + e];
        cn[j] = ig * ug + f1 * c1 + f2 * c2;
        hn[j] = og * ftanh(cn[j]);
      }
      __syncthreads();                       // bar2: C reads done
      // ---- phase D: reduce writes ----
      #pragma unroll
      for (int j = 0; j < 4; ++j){
        const int m = (lane >> 4) * 4 + j;
        if (stOp[s][m] == 1){
          const int sl = stL[s][m];
          hstk[sl * HSLOT + m * 264 + e] = f2bf(hn[j]);
          cstk[sl * HSLOT + m * 264 + e] = cn[j];
          rtop[m * 264 + e] = hn[j];
        }
      }
      __syncthreads();                       // bar3: D visible to next step
    }
  }
  __syncthreads();
  // final root h = rtop (fp32, exact top-of-stack)
  {
    const float* rs = rtop + pm * 264 + pc;
    *(float4*)(r_vec + (size_t)(rb + pm) * DIM + pc) = *(const float4*)(rs);
  }
}

// ---------------- K34: fused vv projection + attention + FC1 (per batch item) ----------------
__global__ __launch_bounds__(256) void k34_attn(
    const float* __restrict__ v, const unsigned short* __restrict__ Wwbf,
    const float* __restrict__ W_b, const float* __restrict__ r_vec,
    const unsigned short* __restrict__ WQbf, const float* __restrict__ WQb,
    const unsigned short* __restrict__ WVbf, const float* __restrict__ WPw,
    const unsigned short* __restrict__ FC1bf, const float* __restrict__ FC1b,
    float* __restrict__ z)
{
  __shared__ unsigned short vvt[196 * 264];     // 103,488 B  bf16 vv tile
  __shared__ char sun[33280];                   // union: vstage dbuf 2x[16][520] u16 / pre [16][264] f32
  __shared__ float scv[216];
  __shared__ float wqv[256];
  __shared__ float rld[256];
  __shared__ float attv[256];
  __shared__ float wpld[256];
  __shared__ float red[8];
  unsigned short* vstage = (unsigned short*)sun;
  float* pre = (float*)sun;

  const int b = blockIdx.x, tid = threadIdx.x;
  const int lane = tid & 63, wv = tid >> 6;
  const int lr = lane & 15, lk = (lane >> 4) * 8;

  rld[tid]  = r_vec[(size_t)b * DIM + tid];
  wpld[tid] = WPw[tid];

  // cache W_w fragments in VGPRs (one-time 256 KB stream per block)
  bf16x8_t Aw[4][16];
  float wbias[4];
  #pragma unroll
  for (int et = 0; et < 4; ++et){
    const int e = et * 64 + wv * 16 + lr;
    wbias[et] = W_b[e];
    const size_t wb = (size_t)e * VDIM + lk;
    #pragma unroll
    for (int kk = 0; kk < 16; ++kk) Aw[et][kk] = *(const bf16x8_t*)(Wwbf + wb + kk * 32);
  }
  // wqq = r @ WQ^T + b (scalar matvec, one output per thread)
  {
    float acc = WQb[tid];
    const unsigned short* wr = WQbf + (size_t)tid * DIM;
    for (int d = 0; d < DIM; d += 8){
      uint4 w4 = *(const uint4*)(wr + d);
      float a0,a1,a2,a3,a4,a5,a6,a7;
      bf2x(w4.x,a0,a1); bf2x(w4.y,a2,a3); bf2x(w4.z,a4,a5); bf2x(w4.w,a6,a7);
      acc += a0*rld[d] + a1*rld[d+1] + a2*rld[d+2] + a3*rld[d+3]
           + a4*rld[d+4] + a5*rld[d+5] + a6*rld[d+6] + a7*rld[d+7];
    }
    wqv[tid] = acc;
  }
  // ---- phase A: vvt = tanh(v[b] @ W_w^T + W_b), T14 reg-staged double buffer ----
  {
    float4 xr[8];
    const int sm = tid >> 4, sc = (tid & 15) * 32;
    // stage tile 0 into buf0
    {
      const float* src = v + ((size_t)b * RREG + sm) * VDIM + sc;
      #pragma unroll
      for (int k = 0; k < 8; ++k) xr[k] = *(const float4*)(src + k * 4);
      unsigned short* dst = vstage + sm * 520 + sc;
      #pragma unroll
      for (int k = 0; k < 8; ++k){
        *(unsigned int*)(dst + k * 4)     = bfpack(xr[k].x, xr[k].y);
        *(unsigned int*)(dst + k * 4 + 2) = bfpack(xr[k].z, xr[k].w);
      }
    }
    for (int t = 0; t < 13; ++t){
      __syncthreads();                      // buf[t&1] ready for all
      // issue next tile's loads (latency hidden under GEMM below)
      const int gr = (t + 1) * 16 + sm;
      if (t < 12 && gr < RREG){
        const float* src = v + ((size_t)b * RREG + gr) * VDIM + sc;
        #pragma unroll
        for (int k = 0; k < 8; ++k) xr[k] = *(const float4*)(src + k * 4);
      }
      // GEMM on buf[t&1]
      const unsigned short* bufc = vstage + (t & 1) * 8320;
      #pragma unroll
      for (int et = 0; et < 4; ++et){
        const int e = et * 64 + wv * 16 + lr;
        f32x4_t acc = {0,0,0,0};
        const unsigned short* ar = bufc + lr * 520 + lk;
        #pragma unroll
        for (int kk = 0; kk < 16; ++kk)
          acc = mfma16(*(const bf16x8_t*)(ar + kk * 32), Aw[et][kk], acc);
        #pragma unroll
        for (int j = 0; j < 4; ++j){
          const int orow = t * 16 + (lane >> 4) * 4 + j;
          if (orow < RREG) vvt[orow * 264 + e] = f2bf(ftanh(acc[j] + wbias[et]));
        }
      }
      // write staged regs to the other buffer
      if (t < 12){
        unsigned short* dst = vstage + ((t + 1) & 1) * 8320 + sm * 520 + sc;
        #pragma unroll
        for (int k = 0; k < 8; ++k){
          *(unsigned int*)(dst + k * 4)     = bfpack(xr[k].x, xr[k].y);
          *(unsigned int*)(dst + k * 4 + 2) = bfpack(xr[k].z, xr[k].w);
        }
      }
    }
  }
  // cache WV fragments in VGPRs for phase B
  bf16x8_t Bv[4][8];
  #pragma unroll
  for (int et = 0; et < 4; ++et){
    const int e = et * 64 + wv * 16 + lr;
    const size_t wb = (size_t)e * DIM + lk;
    #pragma unroll
    for (int kk = 0; kk < 8; ++kk) Bv[et][kk] = *(const bf16x8_t*)(WVbf + wb + kk * 32);
  }
  __syncthreads();
  // ---- phase B: scores ----
  for (int t = 0; t < 13; ++t){
    const int arow = t * 16 + lr;
    const unsigned short* ar = vvt + ((arow < RREG) ? arow : (RREG - 1)) * 264 + lk;
    #pragma unroll
    for (int et = 0; et < 4; ++et){
      const int e = et * 64 + wv * 16 + lr;
      f32x4_t acc = {0,0,0,0};
      #pragma unroll
      for (int kk = 0; kk < 8; ++kk)
        acc = mfma16(*(const bf16x8_t*)(ar + kk * 32), Bv[et][kk], acc);
      const float wqe = wqv[e];
      #pragma unroll
      for (int j = 0; j < 4; ++j){
        const int m = (lane >> 4) * 4 + j;
        pre[m * 264 + e] = ftanh(acc[j] + wqe);
      }
    }
    __syncthreads();
    {
      const int m = tid >> 4, cc = (tid & 15) * 16;
      float p_ = 0.f;
      #pragma unroll
      for (int k = 0; k < 16; ++k) p_ += pre[m * 264 + cc + k] * wpld[cc + k];
      #pragma unroll
      for (int off = 8; off; off >>= 1) p_ += __shfl_xor(p_, off, 16);
      if ((tid & 15) == 0){
        const int rr = t * 16 + m;
        scv[rr] = (rr < RREG) ? p_ : -1e30f;
      }
    }
    __syncthreads();
  }
  // ---- softmax over 196 ----
  {
    const float sv = (tid < RREG) ? scv[tid] : -1e30f;
    float m_ = sv;
    #pragma unroll
    for (int off = 32; off; off >>= 1) m_ = fmaxf(m_, __shfl_xor(m_, off, 64));
    if (lane == 0) red[wv] = m_;
    __syncthreads();
    m_ = fmaxf(fmaxf(red[0], red[1]), fmaxf(red[2], red[3]));
    const float ex = (tid < RREG) ? __expf(sv - m_) : 0.f;
    float s_ = ex;
    #pragma unroll
    for (int off = 32; off; off >>= 1) s_ += __shfl_xor(s_, off, 64);
    if (lane == 0) red[4 + wv] = s_;
    __syncthreads();
    s_ = red[4] + red[5] + red[6] + red[7];
    if (tid < RREG) scv[tid] = ex / s_;
  }
  __syncthreads();
  // ---- att = p . vv + r (vv from LDS) ----
  {
    float a = rld[tid];
    #pragma unroll 4
    for (int rr = 0; rr < RREG; ++rr) a += scv[rr] * bf2f(vvt[rr * 264 + tid]);
    attv[tid] = a;
  }
  __syncthreads();
  // ---- z = tanh(att @ FC1^T + b) ----
  {
    float acc = FC1b[tid];
    const unsigned short* wr = FC1bf + (size_t)tid * DIM;
    for (int d = 0; d < DIM; d += 8){
      uint4 w4 = *(const uint4*)(wr + d);
      float a0,a1,a2,a3,a4,a5,a6,a7;
      bf2x(w4.x,a0,a1); bf2x(w4.y,a2,a3); bf2x(w4.z,a4,a5); bf2x(w4.w,a6,a7);
      acc += a0*attv[d] + a1*attv[d+1] + a2*attv[d+2] + a3*attv[d+3]
           + a4*attv[d+4] + a5*attv[d+5] + a6*attv[d+6] + a7*attv[d+7];
    }
    z[(size_t)b * DIM + tid] = ftanh(acc);
  }
}

// ---------------- K5: FC2 ----------------
__global__ __launch_bounds__(256) void k5_fc2(
    const float* __restrict__ z, const unsigned short* __restrict__ FC2bf,
    const float* __restrict__ FC2b, float* __restrict__ out)
{
  __shared__ unsigned short zt[16][264];
  const int tid = threadIdx.x;
  const int rb = blockIdx.x * 16, ob = blockIdx.y * 64;
  {
    const int m = tid >> 4, c = (tid & 15) * 16;
    const float* src = z + (size_t)(rb + m) * DIM + c;
    #pragma unroll
    for (int k = 0; k < 16; k += 4){
      float4 x = *(const float4*)(src + k);
      *(unsigned int*)&zt[m][c + k]     = bfpack(x.x, x.y);
      *(unsigned int*)&zt[m][c + k + 2] = bfpack(x.z, x.w);
    }
  }
  __syncthreads();
  const int lane = tid & 63, wv = tid >> 6;
  const int lr = lane & 15, lk = (lane >> 4) * 8;
  const int o = ob + wv * 16 + lr;
  f32x4_t acc = {0,0,0,0};
  const size_t wb = (size_t)o * DIM + lk;
  const unsigned short* ar = &zt[lr][lk];
  #pragma unroll
  for (int kk = 0; kk < 8; ++kk){
    bf16x8_t A = *(const bf16x8_t*)(ar + kk * 32);
    bf16x8_t Bb = *(const bf16x8_t*)(FC2bf + wb + kk * 32);
    acc = mfma16(A, Bb, acc);
  }
  if (o < NOUTP){
    const float bo = FC2b[o];
    #pragma unroll
    for (int j = 0; j < 4; ++j){
      const int m = (lane >> 4) * 4 + j;
      out[(size_t)(rb + m) * NOUTP + o] = acc[j] + bo;
    }
  }
}

// ---------------- launch ----------------
extern "C" void kernel_launch(void* const* d_in, const int* in_sizes, int n_in,
                              void* d_out, int out_size, void* d_ws, size_t ws_size,
                              hipStream_t stream) {
  const float* v         = (const float*)d_in[0];
  const int*   questions = (const int*)d_in[1];
  const int*   ops       = (const int*)d_in[2];
  const float* wembed    = (const float*)d_in[4];
  const float* W_w  = (const float*)d_in[5];   const float* W_b  = (const float*)d_in[6];
  const float* Wi_w = (const float*)d_in[7];   const float* Wi_b = (const float*)d_in[8];
  const float* Wu_w = (const float*)d_in[9];   const float* Wu_b = (const float*)d_in[10];
  const float* Wo_w = (const float*)d_in[11];  const float* Wo_b = (const float*)d_in[12];
  const float* Ui_w = (const float*)d_in[13];  const float* Ui_b = (const float*)d_in[14];
  const float* Uf_w = (const float*)d_in[15];  const float* Uf_b = (const float*)d_in[16];
  const float* Uo_w = (const float*)d_in[17];  const float* Uo_b = (const float*)d_in[18];
  const float* Uu_w = (const float*)d_in[19];  const float* Uu_b = (const float*)d_in[20];
  const float* WQ_w = (const float*)d_in[21];  const float* WQ_b = (const float*)d_in[22];
  const float* WV_w = (const float*)d_in[23];
  const float* WP_w = (const float*)d_in[24];
  const float* FC1_w = (const float*)d_in[26]; const float* FC1_b = (const float*)d_in[27];
  const float* FC2_w = (const float*)d_in[28]; const float* FC2_b = (const float*)d_in[29];
  float* out = (float*)d_out;
  char* ws = (char*)d_ws;

  unsigned short* Wwbf  = (unsigned short*)(ws + OFF_WWBF);
  unsigned short* Wibf  = (unsigned short*)(ws + OFF_WIBF);
  unsigned short* Wubf  = (unsigned short*)(ws + OFF_WUBF);
  unsigned short* Wobf  = (unsigned short*)(ws + OFF_WOBF);
  unsigned short* Uibf  = (unsigned short*)(ws + OFF_UIBF);
  unsigned short* Ufbf  = (unsigned short*)(ws + OFF_UFBF);
  unsigned short* Uobf  = (unsigned short*)(ws + OFF_UOBF);
  unsigned short* Uubf  = (unsigned short*)(ws + OFF_UUBF);
  unsigned short* WVbf  = (unsigned short*)(ws + OFF_WVBF);
  unsigned short* WQbf  = (unsigned short*)(ws + OFF_WQBF);
  unsigned short* FC1bf = (unsigned short*)(ws + OFF_FC1BF);
  unsigned short* FC2bf = (unsigned short*)(ws + OFF_FC2BF);
  float* r_vec = (float*)(ws + OFF_RVEC);
  float* z     = (float*)(ws + OFF_Z);
  unsigned short* bh = (unsigned short*)(ws + OFF_BH);
  unsigned short* bc = (unsigned short*)(ws + OFF_BC);

  ConvArgs ca;
  const float* srcs[13] = { W_w, Wi_w, Wu_w, Wo_w, Ui_w, Uf_w, Uo_w, Uu_w, WV_w, WQ_w, FC1_w, FC2_w, nullptr };
  unsigned short* dsts[13] = { Wwbf, Wibf, Wubf, Wobf, Uibf, Ufbf, Uobf, Uubf, WVbf, WQbf, FC1bf, FC2bf, FC2bf + 768000 };
  int ns[13] = { 131072, 65536, 65536, 65536, 65536, 65536, 65536, 65536, 65536, 65536, 65536, 768000, 2048 };
  for (int i = 0; i < 13; ++i){ ca.src[i] = srcs[i]; ca.dst[i] = dsts[i]; ca.n[i] = ns[i]; }
  k0_convert<<<512, 256, 0, stream>>>(ca);

  k1_leaf<<<504, 256, 0, stream>>>(questions, wembed, Wibf, Wubf, Wobf, Wi_b, Wu_b, Wo_b, bh, bc);

  k2_tree<<<32, 1024, 0, stream>>>(ops, bh, bc, Uibf, Ufbf, Uobf, Uubf,
                                   Ui_b, Uf_b, Uo_b, Uu_b, r_vec);

  k34_attn<<<512, 256, 0, stream>>>(v, Wwbf, W_b, r_vec, WQbf, WQ_b, WVbf, WP_w,
                                    FC1bf, FC1_b, z);

  k5_fc2<<<dim3(32, 47), 256, 0, stream>>>(z, FC2bf, FC2_b, out);

  (void)in_sizes; (void)n_in; (void)out_size; (void)ws_size;
}